// Round 1
// 2393.934 us; speedup vs baseline: 1.3194x; 1.3194x over previous
//
#include <hip/hip_runtime.h>

typedef unsigned short u16;
typedef unsigned int u32;
typedef __attribute__((ext_vector_type(8))) short short8;
typedef __attribute__((ext_vector_type(4))) float fx4;

#define BATCH 4096
#define TSEQ 12
#define DIN 1536
#define DS 234
#define KTOT 1770
#define COUT 234

union F4 { float4 v; float f[4]; u32 u[4]; };
union ABFrag { u32 u[4]; short8 s; };

// split x = hi + lo, hi = truncate-to-bf16 (top 16 bits), lo = bf16(x - hi) (truncated).
// |err| <= 2^-16 |x|; with 3-term MFMA (ah*bh + al*bh + ah*bl) product error ~2^-15 rel.
__device__ __forceinline__ void splitPair(float x0, float x1, u32& hi, u32& lo) {
    union { float f; u32 u; } c0, c1, l0, l1;
    union { u32 u; float f; } g0, g1;
    c0.f = x0; c1.f = x1;
    u32 h0 = c0.u & 0xFFFF0000u;
    u32 h1 = c1.u & 0xFFFF0000u;
    g0.u = h0; g1.u = h1;
    l0.f = x0 - g0.f;
    l1.f = x1 - g1.f;
    hi = (h0 >> 16) | h1;
    lo = (l0.u >> 16) | (l1.u & 0xFFFF0000u);
}

// 64-float weight row cached in 16 float4 VGPRs (all-constant indexing after unroll)
__device__ __forceinline__ void loadRow(F4 (&w)[16], const float* base) {
#pragma unroll
    for (int i = 0; i < 16; i++) w[i].v = *(const float4*)(base + 4 * i);
}
__device__ __forceinline__ float dot64(const F4 (&w)[16], const float* v) {
    float a = 0.f, b = 0.f;
#pragma unroll
    for (int i = 0; i < 16; i++) {
        F4 h; h.v = *(const float4*)(v + 4 * i);   // LDS broadcast ds_read_b128
        a += w[i].f[0] * h.f[0] + w[i].f[1] * h.f[1];
        b += w[i].f[2] * h.f[2] + w[i].f[3] * h.f[3];
    }
    return a + b;
}

__global__ __launch_bounds__(64, 3) void k_fused(
    const float* __restrict__ emb, const float* __restrict__ fpass,
    const float* __restrict__ W_in, const float* __restrict__ b_in,
    const float* __restrict__ ln_in_g, const float* __restrict__ ln_in_b,
    const float* __restrict__ site_tab, const float* __restrict__ hour_tab,
    const float* __restrict__ W_meta, const float* __restrict__ b_meta,
    const float* __restrict__ pos_enc,
    const float* __restrict__ Wm, const float* __restrict__ bm,
    const float* __restrict__ lng, const float* __restrict__ lnb,
    const float* __restrict__ Wo, const float* __restrict__ bo,
    const int* __restrict__ site_ids, const int* __restrict__ hours,
    const float* __restrict__ fWxz, const float* __restrict__ fconvw, const float* __restrict__ fconvb,
    const float* __restrict__ fWdt, const float* __restrict__ fbdt, const float* __restrict__ fAlog,
    const float* __restrict__ fDp, const float* __restrict__ fWB, const float* __restrict__ fWC,
    const float* __restrict__ bWxz, const float* __restrict__ bconvw, const float* __restrict__ bconvb,
    const float* __restrict__ bWdt, const float* __restrict__ bbdt, const float* __restrict__ bAlog,
    const float* __restrict__ bDp, const float* __restrict__ bWB, const float* __restrict__ bWC,
    float* __restrict__ out)
{
    // one batch element per 64-thread block: barriers are intra-wave, waves fully decoupled
    __shared__ __attribute__((aligned(16))) float Hs[TSEQ * 64];
    __shared__ __attribute__((aligned(16))) float Xs[TSEQ * 68];
    __shared__ __attribute__((aligned(16))) float BCs[TSEQ * 16];
    __shared__ __attribute__((aligned(16))) float Ys[TSEQ * 128];
    __shared__ __attribute__((aligned(16))) float MTs[64];

    const int lane = threadIdx.x & 63;
    const int q = lane >> 4, cc = lane & 15;
    const int b = blockIdx.x;

    // ---- phase 0: meta vector (lane = channel)
    {
        int sid = min(max(site_ids[b], 0), 19);
        int hr  = min(max(hours[b], 0), 23);
        float a = b_meta[lane];
#pragma unroll
        for (int j = 0; j < 8; j++) a += site_tab[sid * 8 + j] * W_meta[lane * 16 + j];
#pragma unroll
        for (int j = 0; j < 8; j++) a += hour_tab[hr * 8 + j] * W_meta[lane * 16 + 8 + j];
        MTs[lane] = a;
    }

    // ---- phase 1: input GEMM (12x64 <- 12x1770 @ 64x1770^T) via split-bf16 MFMA
    {
        fx4 acc[4];
#pragma unroll
        for (int nt = 0; nt < 4; nt++) acc[nt] = (fx4){0.f, 0.f, 0.f, 0.f};

        const int tA = min(cc, TSEQ - 1);              // A row = cc (rows 12..15 dup row 11, discarded)
        const size_t rb = (size_t)b * TSEQ + tA;
        const float* arow = emb + rb * DIN;            // 16B aligned (1536 % 4 == 0)
        const float* frow = fpass + rb * DS;           // only 8B aligned (234 % 4 != 0)
        const int ko = q * 8;                          // k-offset of this lane's fragment

        // emb part: K = 0..1535
        for (int kg = 0; kg < DIN; kg += 32) {
            F4 a0, a1;
            a0.v = *(const float4*)(arow + kg + ko);
            a1.v = *(const float4*)(arow + kg + ko + 4);
            ABFrag ah, al;
            splitPair(a0.f[0], a0.f[1], ah.u[0], al.u[0]);
            splitPair(a0.f[2], a0.f[3], ah.u[1], al.u[1]);
            splitPair(a1.f[0], a1.f[1], ah.u[2], al.u[2]);
            splitPair(a1.f[2], a1.f[3], ah.u[3], al.u[3]);
#pragma unroll
            for (int nt = 0; nt < 4; nt++) {
                const float* wr = W_in + (size_t)(nt * 16 + cc) * KTOT + kg + ko; // 8B aligned
                float2 w0 = *(const float2*)(wr);
                float2 w1 = *(const float2*)(wr + 2);
                float2 w2 = *(const float2*)(wr + 4);
                float2 w3 = *(const float2*)(wr + 6);
                ABFrag bh, bl;
                splitPair(w0.x, w0.y, bh.u[0], bl.u[0]);
                splitPair(w1.x, w1.y, bh.u[1], bl.u[1]);
                splitPair(w2.x, w2.y, bh.u[2], bl.u[2]);
                splitPair(w3.x, w3.y, bh.u[3], bl.u[3]);
                acc[nt] = __builtin_amdgcn_mfma_f32_16x16x32_bf16(ah.s, bh.s, acc[nt], 0, 0, 0);
                acc[nt] = __builtin_amdgcn_mfma_f32_16x16x32_bf16(al.s, bh.s, acc[nt], 0, 0, 0);
                acc[nt] = __builtin_amdgcn_mfma_f32_16x16x32_bf16(ah.s, bl.s, acc[nt], 0, 0, 0);
            }
        }
        // fpass part, full 32-wide iters: K = 1536..1759 (max elem index 223 < 234)
        for (int kg = 0; kg < 224; kg += 32) {
            float2 a0 = *(const float2*)(frow + kg + ko);
            float2 a1 = *(const float2*)(frow + kg + ko + 2);
            float2 a2 = *(const float2*)(frow + kg + ko + 4);
            float2 a3 = *(const float2*)(frow + kg + ko + 6);
            ABFrag ah, al;
            splitPair(a0.x, a0.y, ah.u[0], al.u[0]);
            splitPair(a1.x, a1.y, ah.u[1], al.u[1]);
            splitPair(a2.x, a2.y, ah.u[2], al.u[2]);
            splitPair(a3.x, a3.y, ah.u[3], al.u[3]);
#pragma unroll
            for (int nt = 0; nt < 4; nt++) {
                const float* wr = W_in + (size_t)(nt * 16 + cc) * KTOT + DIN + kg + ko;
                float2 w0 = *(const float2*)(wr);
                float2 w1 = *(const float2*)(wr + 2);
                float2 w2 = *(const float2*)(wr + 4);
                float2 w3 = *(const float2*)(wr + 6);
                ABFrag bh, bl;
                splitPair(w0.x, w0.y, bh.u[0], bl.u[0]);
                splitPair(w1.x, w1.y, bh.u[1], bl.u[1]);
                splitPair(w2.x, w2.y, bh.u[2], bl.u[2]);
                splitPair(w3.x, w3.y, bh.u[3], bl.u[3]);
                acc[nt] = __builtin_amdgcn_mfma_f32_16x16x32_bf16(ah.s, bh.s, acc[nt], 0, 0, 0);
                acc[nt] = __builtin_amdgcn_mfma_f32_16x16x32_bf16(al.s, bh.s, acc[nt], 0, 0, 0);
                acc[nt] = __builtin_amdgcn_mfma_f32_16x16x32_bf16(ah.s, bl.s, acc[nt], 0, 0, 0);
            }
        }
        // tail: elements 224..233 (10), zero-padded
        {
            float av[8];
#pragma unroll
            for (int j = 0; j < 8; j++) {
                int kk = 224 + ko + j;
                av[j] = (kk < DS) ? frow[kk] : 0.f;
            }
            ABFrag ah, al;
            splitPair(av[0], av[1], ah.u[0], al.u[0]);
            splitPair(av[2], av[3], ah.u[1], al.u[1]);
            splitPair(av[4], av[5], ah.u[2], al.u[2]);
            splitPair(av[6], av[7], ah.u[3], al.u[3]);
#pragma unroll
            for (int nt = 0; nt < 4; nt++) {
                const float* wr = W_in + (size_t)(nt * 16 + cc) * KTOT + DIN + 224 + ko;
                float wv[8];
#pragma unroll
                for (int j = 0; j < 8; j++) {
                    int kk = 224 + ko + j;
                    wv[j] = (kk < DS) ? wr[j] : 0.f;
                }
                ABFrag bh, bl;
                splitPair(wv[0], wv[1], bh.u[0], bl.u[0]);
                splitPair(wv[2], wv[3], bh.u[1], bl.u[1]);
                splitPair(wv[4], wv[5], bh.u[2], bl.u[2]);
                splitPair(wv[6], wv[7], bh.u[3], bl.u[3]);
                acc[nt] = __builtin_amdgcn_mfma_f32_16x16x32_bf16(ah.s, bh.s, acc[nt], 0, 0, 0);
                acc[nt] = __builtin_amdgcn_mfma_f32_16x16x32_bf16(al.s, bh.s, acc[nt], 0, 0, 0);
                acc[nt] = __builtin_amdgcn_mfma_f32_16x16x32_bf16(ah.s, bl.s, acc[nt], 0, 0, 0);
            }
        }
        // epilogue: C/D col = nt*16+cc, row t = q*4+r (rows 12..15 discarded)
        float bia[4], gg[4], bb2[4];
#pragma unroll
        for (int nt = 0; nt < 4; nt++) {
            int col = nt * 16 + cc;
            bia[nt] = b_in[col]; gg[nt] = ln_in_g[col]; bb2[nt] = ln_in_b[col];
        }
#pragma unroll
        for (int r = 0; r < 4; r++) {
            float vv[4], s1 = 0.f, s2 = 0.f;
#pragma unroll
            for (int nt = 0; nt < 4; nt++) {
                vv[nt] = acc[nt][r] + bia[nt];
                s1 += vv[nt]; s2 += vv[nt] * vv[nt];
            }
#pragma unroll
            for (int off = 1; off <= 8; off <<= 1) {
                s1 += __shfl_xor(s1, off);
                s2 += __shfl_xor(s2, off);
            }
            if (q < 3) {
                int t = q * 4 + r;
                float mean = s1 * 0.015625f;
                float var = s2 * 0.015625f - mean * mean;
                float rstd = rsqrtf(var + 1e-5f);
#pragma unroll
                for (int nt = 0; nt < 4; nt++) {
                    int col = nt * 16 + cc;
                    float x = (vv[nt] - mean) * rstd * gg[nt] + bb2[nt];
                    float gel = 0.5f * x * (1.f + erff(x * 0.70710678118654752f));
                    Hs[t * 64 + col] = gel + pos_enc[t * 64 + col] + MTs[col];
                }
            }
        }
    }
    __syncthreads();   // single-wave block: ~free, guarantees LDS visibility

    // ---- phase 2: bidirectional SSM (lane = channel d)
#pragma unroll 1
    for (int dir = 0; dir < 2; dir++) {
        const float* Wxz  = dir ? bWxz  : fWxz;
        const float* cw   = dir ? bconvw : fconvw;
        const float* cbp  = dir ? bconvb : fconvb;
        const float* Wdt  = dir ? bWdt  : fWdt;
        const float* bdt  = dir ? bbdt  : fbdt;
        const float* Alog = dir ? bAlog : fAlog;
        const float* Dp   = dir ? bDp   : fDp;
        const float* WB   = dir ? bWB   : fWB;
        const float* WC   = dir ? bWC   : fWC;

        float xs[TSEQ];
        {
            F4 rw[16]; loadRow(rw, Wxz + lane * 64);   // hoisted: loaded once, reused 12x
#pragma unroll
            for (int s = 0; s < TSEQ; s++) {
                int t = dir ? (TSEQ - 1 - s) : s;
                xs[s] = dot64(rw, Hs + t * 64);
            }
        }
        {
            float w0 = cw[lane * 4 + 0], w1 = cw[lane * 4 + 1];
            float w2 = cw[lane * 4 + 2], w3 = cw[lane * 4 + 3];
            float cb = cbp[lane];
#pragma unroll
            for (int s = 0; s < TSEQ; s++) {
                float a = cb + w3 * xs[s];
                if (s >= 1) a += w2 * xs[s - 1];
                if (s >= 2) a += w1 * xs[s - 2];
                if (s >= 3) a += w0 * xs[s - 3];
                float sig = 1.f / (1.f + __expf(-a));
                Xs[s * 68 + lane] = a * sig;
            }
        }
        __syncthreads();

        float dtv[TSEQ];
        {
            F4 rw[16]; loadRow(rw, Wdt + lane * 64);
            float bdv = bdt[lane];
#pragma unroll
            for (int s = 0; s < TSEQ; s++) {
                float a = bdv + dot64(rw, Xs + s * 68);
                dtv[s] = fmaxf(a, 0.f) + log1pf(__expf(-fabsf(a)));
            }
        }
        {
            // lane -> (s1 = lane>>3, n = lane&7); lanes<32 also cover s2 = 8 + (lane>>3)
            const int n = lane & 7, s1 = lane >> 3;
#pragma unroll 1
            for (int sel = 0; sel < 2; sel++) {        // 0 = B, 1 = C (sequential: caps VGPR)
                F4 rw[16]; loadRow(rw, (sel ? WC : WB) + n * 64);
                BCs[s1 * 16 + sel * 8 + n] = dot64(rw, Xs + s1 * 68);
                if (lane < 32)
                    BCs[(8 + s1) * 16 + sel * 8 + n] = dot64(rw, Xs + (8 + s1) * 68);
            }
        }
        __syncthreads();

        {
            float An[8];
#pragma unroll
            for (int n2 = 0; n2 < 8; n2++) An[n2] = -__expf(Alog[lane * 8 + n2]);
            float dpv = Dp[lane];
            float st[8] = {0.f, 0.f, 0.f, 0.f, 0.f, 0.f, 0.f, 0.f};
#pragma unroll
            for (int s = 0; s < TSEQ; s++) {
                int t = dir ? (TSEQ - 1 - s) : s;
                float dtc = dtv[s];
                float xv = Hs[t * 64 + lane];
                float coef = xv * dtc;
                const float* bcp = BCs + s * 16;
                float y = 0.f;
#pragma unroll
                for (int n2 = 0; n2 < 8; n2++) {
                    float dA = __expf(An[n2] * dtc);
                    st[n2] = st[n2] * dA + coef * bcp[n2];
                    y += st[n2] * bcp[8 + n2];
                }
                Ys[t * 128 + (dir << 6) + lane] = y + xv * dpv;
            }
        }
        __syncthreads();
    }

    // ---- phase 3: merge + residual + LN -> Xs
    {
        float mv[TSEQ];
        float bmv = bm[lane];
#pragma unroll
        for (int t = 0; t < TSEQ; t++) mv[t] = bmv + Hs[t * 64 + lane];
#pragma unroll 1
        for (int half = 0; half < 2; half++) {
            F4 rw[16]; loadRow(rw, Wm + lane * 128 + half * 64);
#pragma unroll
            for (int t = 0; t < TSEQ; t++) mv[t] += dot64(rw, Ys + t * 128 + half * 64);
        }
        float g = lng[lane], be = lnb[lane];
#pragma unroll
        for (int t = 0; t < TSEQ; t++) {
            float v = mv[t];
            float s1 = v, s2 = v * v;
#pragma unroll
            for (int off = 1; off <= 32; off <<= 1) {
                s1 += __shfl_xor(s1, off);
                s2 += __shfl_xor(s2, off);
            }
            float mean = s1 * 0.015625f;
            float var = s2 * 0.015625f - mean * mean;
            float rs = rsqrtf(var + 1e-5f);
            Xs[t * 68 + lane] = (v - mean) * rs * g + be;
        }
    }
    __syncthreads();

    // ---- phase 4: out projection (234 cols in 4 chunks of 64 lanes)
#pragma unroll 1
    for (int ci = 0; ci < 4; ci++) {
        int cidx = ci * 64 + lane;
        bool act = cidx < COUT;
        F4 rw[16];
        float bov = 0.f;
        if (act) { loadRow(rw, Wo + (size_t)cidx * 64); bov = bo[cidx]; }
        for (int t = 0; t < TSEQ; t++) {
            if (act) {
                float a = bov + dot64(rw, Xs + t * 68);
                out[((size_t)b * TSEQ + t) * COUT + cidx] = a;
            }
        }
    }
}

// ---------------- host ---------------------------------------------------------------------
extern "C" void kernel_launch(void* const* d_in, const int* in_sizes, int n_in,
                              void* d_out, int out_size, void* d_ws, size_t ws_size,
                              hipStream_t stream) {
    (void)d_ws; (void)ws_size; (void)in_sizes; (void)n_in; (void)out_size;

    k_fused<<<BATCH, 64, 0, stream>>>(
        (const float*)d_in[0], (const float*)d_in[1], (const float*)d_in[2], (const float*)d_in[3],
        (const float*)d_in[4], (const float*)d_in[5],
        (const float*)d_in[6], (const float*)d_in[7], (const float*)d_in[8], (const float*)d_in[9],
        (const float*)d_in[10],
        (const float*)d_in[11], (const float*)d_in[12], (const float*)d_in[13], (const float*)d_in[14],
        (const float*)d_in[15], (const float*)d_in[16],
        (const int*)d_in[17], (const int*)d_in[18],
        (const float*)d_in[19], (const float*)d_in[20], (const float*)d_in[21], (const float*)d_in[22],
        (const float*)d_in[23], (const float*)d_in[24], (const float*)d_in[25], (const float*)d_in[26],
        (const float*)d_in[27],
        (const float*)d_in[28], (const float*)d_in[29], (const float*)d_in[30], (const float*)d_in[31],
        (const float*)d_in[32], (const float*)d_in[33], (const float*)d_in[34], (const float*)d_in[35],
        (const float*)d_in[36],
        (float*)d_out);
}

// Round 2
// 1306.713 us; speedup vs baseline: 2.4171x; 1.8320x over previous
//
#include <hip/hip_runtime.h>

typedef unsigned short u16;
typedef unsigned int u32;
typedef __attribute__((ext_vector_type(8))) short short8;
typedef __attribute__((ext_vector_type(4))) float fx4;

#define BATCH 4096
#define TSEQ 12
#define DIN 1536
#define DS 234
#define KTOT 1770
#define KPAD 1792
#define COUT 234
#define MROWS (BATCH * TSEQ)   // 49152

union F4 { float4 v; float f[4]; u32 u[4]; };
union ABFrag { u32 u[4]; short8 s; uint4 q4; };

// persistent intermediates (module-static: no hipMalloc inside kernel_launch)
__device__ __attribute__((aligned(256))) u16 gWhi[64 * KPAD];
__device__ __attribute__((aligned(256))) u16 gWlo[64 * KPAD];
__device__ __attribute__((aligned(256))) float gH[(size_t)MROWS * 64];

// split x = hi + lo, hi = truncate-to-bf16 (top 16 bits), lo = bf16(x - hi).
// 3-term MFMA (ah*bh + al*bh + ah*bl) -> ~2^-15 relative product error.
__device__ __forceinline__ void splitPair(float x0, float x1, u32& hi, u32& lo) {
    union { float f; u32 u; } c0, c1, l0, l1;
    union { u32 u; float f; } g0, g1;
    c0.f = x0; c1.f = x1;
    u32 h0 = c0.u & 0xFFFF0000u;
    u32 h1 = c1.u & 0xFFFF0000u;
    g0.u = h0; g1.u = h1;
    l0.f = x0 - g0.f;
    l1.f = x1 - g1.f;
    hi = (h0 >> 16) | h1;
    lo = (l0.u >> 16) | (l1.u & 0xFFFF0000u);
}

__device__ __forceinline__ void splitFrag(const float a[8], ABFrag& ah, ABFrag& al) {
#pragma unroll
    for (int i = 0; i < 4; i++) splitPair(a[2 * i], a[2 * i + 1], ah.u[i], al.u[i]);
}

// 64-float weight row cached in 16 float4 VGPRs
__device__ __forceinline__ void loadRow(F4 (&w)[16], const float* base) {
#pragma unroll
    for (int i = 0; i < 16; i++) w[i].v = *(const float4*)(base + 4 * i);
}
__device__ __forceinline__ float dot64(const F4 (&w)[16], const float* v) {
    float a = 0.f, b = 0.f;
#pragma unroll
    for (int i = 0; i < 16; i++) {
        F4 h; h.v = *(const float4*)(v + 4 * i);   // LDS broadcast ds_read_b128
        a += w[i].f[0] * h.f[0] + w[i].f[1] * h.f[1];
        b += w[i].f[2] * h.f[2] + w[i].f[3] * h.f[3];
    }
    return a + b;
}

// ---------------- kernel 0: W_in -> bf16 hi/lo planes (K zero-padded to 1792) -------------
__global__ __launch_bounds__(256) void k_wsplit(const float* __restrict__ W_in) {
    int idx = blockIdx.x * 256 + threadIdx.x;        // 0 .. 64*1792-1
    int n = idx / KPAD, k = idx - n * KPAD;
    float w = (k < KTOT) ? W_in[n * KTOT + k] : 0.f;
    union { float f; u32 u; } c; c.f = w;
    u32 h = c.u & 0xFFFF0000u;
    union { u32 u; float f; } g; g.u = h;
    union { float f; u32 u; } l; l.f = w - g.f;
    gWhi[idx] = (u16)(h >> 16);
    gWlo[idx] = (u16)(l.u >> 16);
}

// ---------------- kernel 1: H = gelu(LN(X @ W^T + b)) ; X = [emb | fpass] ------------------
// one wave per block; each wave computes 64 M-rows x 64 cols, K = 1770.
__global__ __launch_bounds__(64) void k_gemm(
    const float* __restrict__ emb, const float* __restrict__ fpass,
    const float* __restrict__ b_in, const float* __restrict__ ln_in_g,
    const float* __restrict__ ln_in_b)
{
    const int lane = threadIdx.x;
    const int q = lane >> 4, cc = lane & 15;
    const int ko = q * 8;
    const int rowblk = blockIdx.x * 64;

    fx4 acc[4][4];
#pragma unroll
    for (int tl = 0; tl < 4; tl++)
#pragma unroll
        for (int nt = 0; nt < 4; nt++) acc[tl][nt] = (fx4){0.f, 0.f, 0.f, 0.f};

    const float* arows[4];
    const float* frows[4];
#pragma unroll
    for (int tl = 0; tl < 4; tl++) {
        size_t m = (size_t)(rowblk + tl * 16 + cc);
        arows[tl] = emb + m * DIN + ko;
        frows[tl] = fpass + m * DS + ko;
    }
    const u16* whb = gWhi + cc * KPAD + ko;
    const u16* wlb = gWlo + cc * KPAD + ko;

    // emb part: K = 0..1535
    for (int kg = 0; kg < DIN; kg += 32) {
        ABFrag bh[4], bl[4];
#pragma unroll
        for (int nt = 0; nt < 4; nt++) {
            bh[nt].q4 = *(const uint4*)(whb + nt * 16 * KPAD + kg);
            bl[nt].q4 = *(const uint4*)(wlb + nt * 16 * KPAD + kg);
        }
#pragma unroll
        for (int tl = 0; tl < 4; tl++) {
            F4 a0, a1;
            a0.v = *(const float4*)(arows[tl] + kg);
            a1.v = *(const float4*)(arows[tl] + kg + 4);
            float av[8] = {a0.f[0], a0.f[1], a0.f[2], a0.f[3], a1.f[0], a1.f[1], a1.f[2], a1.f[3]};
            ABFrag ah, al;
            splitFrag(av, ah, al);
#pragma unroll
            for (int nt = 0; nt < 4; nt++) {
                acc[tl][nt] = __builtin_amdgcn_mfma_f32_16x16x32_bf16(ah.s, bh[nt].s, acc[tl][nt], 0, 0, 0);
                acc[tl][nt] = __builtin_amdgcn_mfma_f32_16x16x32_bf16(al.s, bh[nt].s, acc[tl][nt], 0, 0, 0);
                acc[tl][nt] = __builtin_amdgcn_mfma_f32_16x16x32_bf16(ah.s, bl[nt].s, acc[tl][nt], 0, 0, 0);
            }
        }
    }
    // fpass part, full 32-wide steps: K = 1536..1759 (elem idx <= 223 < 234)
    for (int kg = 0; kg < 224; kg += 32) {
        ABFrag bh[4], bl[4];
#pragma unroll
        for (int nt = 0; nt < 4; nt++) {
            bh[nt].q4 = *(const uint4*)(whb + nt * 16 * KPAD + DIN + kg);
            bl[nt].q4 = *(const uint4*)(wlb + nt * 16 * KPAD + DIN + kg);
        }
#pragma unroll
        for (int tl = 0; tl < 4; tl++) {
            float2 a0 = *(const float2*)(frows[tl] + kg);
            float2 a1 = *(const float2*)(frows[tl] + kg + 2);
            float2 a2 = *(const float2*)(frows[tl] + kg + 4);
            float2 a3 = *(const float2*)(frows[tl] + kg + 6);
            float av[8] = {a0.x, a0.y, a1.x, a1.y, a2.x, a2.y, a3.x, a3.y};
            ABFrag ah, al;
            splitFrag(av, ah, al);
#pragma unroll
            for (int nt = 0; nt < 4; nt++) {
                acc[tl][nt] = __builtin_amdgcn_mfma_f32_16x16x32_bf16(ah.s, bh[nt].s, acc[tl][nt], 0, 0, 0);
                acc[tl][nt] = __builtin_amdgcn_mfma_f32_16x16x32_bf16(al.s, bh[nt].s, acc[tl][nt], 0, 0, 0);
                acc[tl][nt] = __builtin_amdgcn_mfma_f32_16x16x32_bf16(ah.s, bl[nt].s, acc[tl][nt], 0, 0, 0);
            }
        }
    }
    // tail: elems 224..233 of fpass (W planes are zero-padded past 1770)
    {
        ABFrag bh[4], bl[4];
#pragma unroll
        for (int nt = 0; nt < 4; nt++) {
            bh[nt].q4 = *(const uint4*)(whb + nt * 16 * KPAD + DIN + 224);
            bl[nt].q4 = *(const uint4*)(wlb + nt * 16 * KPAD + DIN + 224);
        }
#pragma unroll
        for (int tl = 0; tl < 4; tl++) {
            float av[8];
#pragma unroll
            for (int j = 0; j < 8; j++) {
                int kk = 224 + ko + j;
                av[j] = (kk < DS) ? frows[tl][224 + j] : 0.f;
            }
            ABFrag ah, al;
            splitFrag(av, ah, al);
#pragma unroll
            for (int nt = 0; nt < 4; nt++) {
                acc[tl][nt] = __builtin_amdgcn_mfma_f32_16x16x32_bf16(ah.s, bh[nt].s, acc[tl][nt], 0, 0, 0);
                acc[tl][nt] = __builtin_amdgcn_mfma_f32_16x16x32_bf16(al.s, bh[nt].s, acc[tl][nt], 0, 0, 0);
                acc[tl][nt] = __builtin_amdgcn_mfma_f32_16x16x32_bf16(ah.s, bl[nt].s, acc[tl][nt], 0, 0, 0);
            }
        }
    }
    // epilogue: bias + LN(64) + GELU -> gH.  C/D: col = nt*16+cc, row = q*4+reg.
    float bia[4], gg[4], bb2[4];
#pragma unroll
    for (int nt = 0; nt < 4; nt++) {
        int col = nt * 16 + cc;
        bia[nt] = b_in[col]; gg[nt] = ln_in_g[col]; bb2[nt] = ln_in_b[col];
    }
#pragma unroll
    for (int tl = 0; tl < 4; tl++) {
#pragma unroll
        for (int rr = 0; rr < 4; rr++) {
            float vv[4], s1 = 0.f, s2 = 0.f;
#pragma unroll
            for (int nt = 0; nt < 4; nt++) {
                vv[nt] = acc[tl][nt][rr] + bia[nt];
                s1 += vv[nt]; s2 += vv[nt] * vv[nt];
            }
#pragma unroll
            for (int off = 1; off <= 8; off <<= 1) {
                s1 += __shfl_xor(s1, off);
                s2 += __shfl_xor(s2, off);
            }
            float mean = s1 * 0.015625f;
            float var = s2 * 0.015625f - mean * mean;
            float rstd = rsqrtf(var + 1e-5f);
            size_t m = (size_t)(rowblk + tl * 16 + q * 4 + rr);
#pragma unroll
            for (int nt = 0; nt < 4; nt++) {
                float x = (vv[nt] - mean) * rstd * gg[nt] + bb2[nt];
                float gel = 0.5f * x * (1.f + erff(x * 0.70710678118654752f));
                gH[m * 64 + nt * 16 + cc] = gel;
            }
        }
    }
}

// ---------------- kernel 2: meta + pos + bidirectional SSM + merge + LN + out --------------
__global__ __launch_bounds__(64) void k_ssm(
    const float* __restrict__ site_tab, const float* __restrict__ hour_tab,
    const float* __restrict__ W_meta, const float* __restrict__ b_meta,
    const float* __restrict__ pos_enc,
    const float* __restrict__ Wm, const float* __restrict__ bm,
    const float* __restrict__ lng, const float* __restrict__ lnb,
    const float* __restrict__ Wo, const float* __restrict__ bo,
    const int* __restrict__ site_ids, const int* __restrict__ hours,
    const float* __restrict__ fWxz, const float* __restrict__ fconvw, const float* __restrict__ fconvb,
    const float* __restrict__ fWdt, const float* __restrict__ fbdt, const float* __restrict__ fAlog,
    const float* __restrict__ fDp, const float* __restrict__ fWB, const float* __restrict__ fWC,
    const float* __restrict__ bWxz, const float* __restrict__ bconvw, const float* __restrict__ bconvb,
    const float* __restrict__ bWdt, const float* __restrict__ bbdt, const float* __restrict__ bAlog,
    const float* __restrict__ bDp, const float* __restrict__ bWB, const float* __restrict__ bWC,
    float* __restrict__ out)
{
    __shared__ __attribute__((aligned(16))) float Hs[TSEQ * 64];
    __shared__ __attribute__((aligned(16))) float Xs[TSEQ * 64];
    __shared__ __attribute__((aligned(16))) float BCs[TSEQ * 16];
    __shared__ __attribute__((aligned(16))) float Ys[TSEQ * 128];

    const int lane = threadIdx.x;
    const int b = blockIdx.x;

    // meta for this lane's channel (register, no LDS needed)
    float metaV;
    {
        int sid = min(max(site_ids[b], 0), 19);
        int hr  = min(max(hours[b], 0), 23);
        float a = b_meta[lane];
#pragma unroll
        for (int j = 0; j < 8; j++) a += site_tab[sid * 8 + j] * W_meta[lane * 16 + j];
#pragma unroll
        for (int j = 0; j < 8; j++) a += hour_tab[hr * 8 + j] * W_meta[lane * 16 + 8 + j];
        metaV = a;
    }
    // H load + pos + meta
#pragma unroll
    for (int t = 0; t < TSEQ; t++)
        Hs[t * 64 + lane] = gH[((size_t)b * TSEQ + t) * 64 + lane] + pos_enc[t * 64 + lane] + metaV;
    __syncthreads();

    // ---- bidirectional SSM (lane = channel d)
#pragma unroll 1
    for (int dir = 0; dir < 2; dir++) {
        const float* Wxz  = dir ? bWxz  : fWxz;
        const float* cw   = dir ? bconvw : fconvw;
        const float* cbp  = dir ? bconvb : fconvb;
        const float* Wdt  = dir ? bWdt  : fWdt;
        const float* bdt  = dir ? bbdt  : fbdt;
        const float* Alog = dir ? bAlog : fAlog;
        const float* Dp   = dir ? bDp   : fDp;
        const float* WB   = dir ? bWB   : fWB;
        const float* WC   = dir ? bWC   : fWC;

        float xs[TSEQ];
        {
            F4 rw[16]; loadRow(rw, Wxz + lane * 64);
#pragma unroll
            for (int s = 0; s < TSEQ; s++) {
                int t = dir ? (TSEQ - 1 - s) : s;
                xs[s] = dot64(rw, Hs + t * 64);
            }
        }
        {
            float w0 = cw[lane * 4 + 0], w1 = cw[lane * 4 + 1];
            float w2 = cw[lane * 4 + 2], w3 = cw[lane * 4 + 3];
            float cb = cbp[lane];
#pragma unroll
            for (int s = 0; s < TSEQ; s++) {
                float a = cb + w3 * xs[s];
                if (s >= 1) a += w2 * xs[s - 1];
                if (s >= 2) a += w1 * xs[s - 2];
                if (s >= 3) a += w0 * xs[s - 3];
                float sig = 1.f / (1.f + __expf(-a));
                Xs[s * 64 + lane] = a * sig;
            }
        }
        __syncthreads();

        float dtv[TSEQ];
        {
            F4 rw[16]; loadRow(rw, Wdt + lane * 64);
            float bdv = bdt[lane];
#pragma unroll
            for (int s = 0; s < TSEQ; s++) {
                float a = bdv + dot64(rw, Xs + s * 64);
                dtv[s] = fmaxf(a, 0.f) + log1pf(__expf(-fabsf(a)));
            }
        }
        {
            // lane -> (s1 = lane>>3, n = lane&7); lanes<32 also cover s = 8 + (lane>>3)
            const int n = lane & 7, s1 = lane >> 3;
#pragma unroll 1
            for (int sel = 0; sel < 2; sel++) {
                F4 rw[16]; loadRow(rw, (sel ? WC : WB) + n * 64);
                BCs[s1 * 16 + sel * 8 + n] = dot64(rw, Xs + s1 * 64);
                if (lane < 32)
                    BCs[(8 + s1) * 16 + sel * 8 + n] = dot64(rw, Xs + (8 + s1) * 64);
            }
        }
        __syncthreads();

        {
            float An[8];
#pragma unroll
            for (int n2 = 0; n2 < 8; n2++) An[n2] = -__expf(Alog[lane * 8 + n2]);
            float dpv = Dp[lane];
            float st[8] = {0.f, 0.f, 0.f, 0.f, 0.f, 0.f, 0.f, 0.f};
#pragma unroll
            for (int s = 0; s < TSEQ; s++) {
                int t = dir ? (TSEQ - 1 - s) : s;
                float dtc = dtv[s];
                float xv = Hs[t * 64 + lane];
                float coef = xv * dtc;
                const float* bcp = BCs + s * 16;
                float y = 0.f;
#pragma unroll
                for (int n2 = 0; n2 < 8; n2++) {
                    float dA = __expf(An[n2] * dtc);
                    st[n2] = st[n2] * dA + coef * bcp[n2];
                    y += st[n2] * bcp[8 + n2];
                }
                Ys[t * 128 + (dir << 6) + lane] = y + xv * dpv;
            }
        }
        __syncthreads();
    }

    // ---- merge + residual + LN -> Xs
    {
        float mv[TSEQ];
        float bmv = bm[lane];
#pragma unroll
        for (int t = 0; t < TSEQ; t++) mv[t] = bmv + Hs[t * 64 + lane];
#pragma unroll 1
        for (int half = 0; half < 2; half++) {
            F4 rw[16]; loadRow(rw, Wm + lane * 128 + half * 64);
#pragma unroll
            for (int t = 0; t < TSEQ; t++) mv[t] += dot64(rw, Ys + t * 128 + half * 64);
        }
        float g = lng[lane], be = lnb[lane];
#pragma unroll
        for (int t = 0; t < TSEQ; t++) {
            float v = mv[t];
            float s1 = v, s2 = v * v;
#pragma unroll
            for (int off = 1; off <= 32; off <<= 1) {
                s1 += __shfl_xor(s1, off);
                s2 += __shfl_xor(s2, off);
            }
            float mean = s1 * 0.015625f;
            float var = s2 * 0.015625f - mean * mean;
            float rs = rsqrtf(var + 1e-5f);
            Xs[t * 64 + lane] = (v - mean) * rs * g + be;
        }
    }
    __syncthreads();

    // ---- out projection (234 cols in 4 chunks of 64 lanes)
#pragma unroll 1
    for (int ci = 0; ci < 4; ci++) {
        int cidx = ci * 64 + lane;
        bool act = cidx < COUT;
        F4 rw[16];
        float bov = 0.f;
        if (act) { loadRow(rw, Wo + (size_t)cidx * 64); bov = bo[cidx]; }
        for (int t = 0; t < TSEQ; t++) {
            if (act) {
                float a = bov + dot64(rw, Xs + t * 64);
                out[((size_t)b * TSEQ + t) * COUT + cidx] = a;
            }
        }
    }
}

// ---------------- host ---------------------------------------------------------------------
extern "C" void kernel_launch(void* const* d_in, const int* in_sizes, int n_in,
                              void* d_out, int out_size, void* d_ws, size_t ws_size,
                              hipStream_t stream) {
    (void)d_ws; (void)ws_size; (void)in_sizes; (void)n_in; (void)out_size;

    k_wsplit<<<(64 * KPAD) / 256, 256, 0, stream>>>((const float*)d_in[2]);

    k_gemm<<<MROWS / 64, 64, 0, stream>>>(
        (const float*)d_in[0], (const float*)d_in[1],
        (const float*)d_in[3], (const float*)d_in[4], (const float*)d_in[5]);

    k_ssm<<<BATCH, 64, 0, stream>>>(
        (const float*)d_in[6], (const float*)d_in[7], (const float*)d_in[8], (const float*)d_in[9],
        (const float*)d_in[10],
        (const float*)d_in[11], (const float*)d_in[12], (const float*)d_in[13], (const float*)d_in[14],
        (const float*)d_in[15], (const float*)d_in[16],
        (const int*)d_in[17], (const int*)d_in[18],
        (const float*)d_in[19], (const float*)d_in[20], (const float*)d_in[21], (const float*)d_in[22],
        (const float*)d_in[23], (const float*)d_in[24], (const float*)d_in[25], (const float*)d_in[26],
        (const float*)d_in[27],
        (const float*)d_in[28], (const float*)d_in[29], (const float*)d_in[30], (const float*)d_in[31],
        (const float*)d_in[32], (const float*)d_in[33], (const float*)d_in[34], (const float*)d_in[35],
        (const float*)d_in[36],
        (float*)d_out);
}